// Round 19
// baseline (120.958 us; speedup 1.0000x reference)
//
#include <hip/hip_runtime.h>
#include <stdint.h>

typedef unsigned long long u64;

#define CHUNK 32
#define WARM  8
#define SLEN  (WARM + CHUNK)        // 40 steps per chunk window
#define CPW   8                     // chunks per wave (8 lanes each)
#define PD    8
#define NB    16384
#define NR    1024                  // regions of 16 buckets
#define BCAP  128                   // max keys per bucket (Poisson mean 64)
#define RCAP  2048                  // max elems per region (mean 1024)
#define HBLK  64                    // hist partial blocks
#define LOG2PI_F 1.8378770664093453f

// ---------------- region histogram: per-block partials, no atomics -----------
__device__ __forceinline__ int bucket_of(float tv, float scale) {
    int b = (int)(tv * scale);
    return b > (NB - 1) ? (NB - 1) : (b < 0 ? 0 : b);
}

__global__ __launch_bounds__(256) void hist_k(const float4* __restrict__ t4,
                                              unsigned* __restrict__ hp,
                                              float scale, int n4) {
    __shared__ unsigned lh[NR];
    for (int v = threadIdx.x; v < NR; v += 256) lh[v] = 0u;
    __syncthreads();
    for (int i = blockIdx.x * 256 + threadIdx.x; i < n4; i += gridDim.x * 256) {
        float4 tv = t4[i];
        atomicAdd(&lh[bucket_of(tv.x, scale) >> 4], 1u);
        atomicAdd(&lh[bucket_of(tv.y, scale) >> 4], 1u);
        atomicAdd(&lh[bucket_of(tv.z, scale) >> 4], 1u);
        atomicAdd(&lh[bucket_of(tv.w, scale) >> 4], 1u);
    }
    __syncthreads();
    for (int v = threadIdx.x; v < NR; v += 256)
        hp[blockIdx.x * NR + v] = lh[v];
}

// ---- region scan: sum 64 partials per region, scan 1024 (1 block) -----------
__global__ __launch_bounds__(1024) void scan_k(const unsigned* __restrict__ hp,
                                               unsigned* __restrict__ roff,
                                               unsigned* __restrict__ rcnt) {
    __shared__ unsigned ws[16];
    const int r = threadIdx.x;           // 0..1023 = region
    unsigned tot = 0;
#pragma unroll 8
    for (int b = 0; b < HBLK; ++b) tot += hp[b * NR + r];
    unsigned s = tot;                    // inclusive scan within wave
#pragma unroll
    for (int d = 1; d < 64; d <<= 1) {
        unsigned v = __shfl_up(s, d);
        if ((r & 63) >= d) s += v;
    }
    if ((r & 63) == 63) ws[r >> 6] = s;
    __syncthreads();
    if (r < 16) {
        unsigned v = ws[r];
#pragma unroll
        for (int d = 1; d < 16; d <<= 1) {
            unsigned x = __shfl_up(v, d);
            if (r >= d) v += x;
        }
        ws[r] = v;
    }
    __syncthreads();
    unsigned wbase = (r >= 64) ? ws[(r >> 6) - 1] : 0u;
    unsigned excl = wbase + s - tot;
    roff[r] = excl; rcnt[r] = excl;
    if (r == NR - 1) roff[NR] = excl + tot;
}

// ------- scatter: block-aggregated keys + (y,d) payload into 1024 regions ----
// key = tbits<<32 | idx<<11 | slot (slot = pos within region, 11 bits).
// Order is (tbits, idx); idx unique -> slot never affects order (determinism).
__global__ __launch_bounds__(1024) void scatter1(const float4* __restrict__ t4,
                                                 const float4* __restrict__ y4,
                                                 const float4* __restrict__ e4,
                                                 const unsigned* __restrict__ roff,
                                                 unsigned* __restrict__ rcnt,
                                                 u64* __restrict__ keys1,
                                                 float2* __restrict__ pay1,
                                                 float scale) {
    __shared__ unsigned lh[NR], rb[NR], rloc[NR];
    const int tid = threadIdx.x;
    lh[tid] = 0u;
    __syncthreads();
    const int i0 = blockIdx.x * 2048 + tid;     // 2048 float4 per block
    float4 a = t4[i0], b = t4[i0 + 1024];
    float4 ya = y4[i0], yb = y4[i0 + 1024];
    float4 ea = e4[i0], eb = e4[i0 + 1024];
    float tv[8] = {a.x, a.y, a.z, a.w, b.x, b.y, b.z, b.w};
    float yv[8] = {ya.x, ya.y, ya.z, ya.w, yb.x, yb.y, yb.z, yb.w};
    float ev[8] = {ea.x, ea.y, ea.z, ea.w, eb.x, eb.y, eb.z, eb.w};
    unsigned id0 = 4u * (unsigned)i0, id1 = 4u * (unsigned)(i0 + 1024);
    unsigned ids[8] = {id0, id0 + 1, id0 + 2, id0 + 3,
                       id1, id1 + 1, id1 + 2, id1 + 3};
    int rr[8]; unsigned lp[8];
#pragma unroll
    for (int k = 0; k < 8; ++k) {
        rr[k] = bucket_of(tv[k], scale) >> 4;
        lp[k] = atomicAdd(&lh[rr[k]], 1u);
    }
    __syncthreads();
    {
        unsigned c = lh[tid];
        unsigned base = c ? atomicAdd(&rcnt[tid], c) : 0u;
        rb[tid] = base;
        rloc[tid] = base - roff[tid];
    }
    __syncthreads();
#pragma unroll
    for (int k = 0; k < 8; ++k) {
        unsigned bits = __float_as_uint(tv[k]);
        unsigned mk = (bits & 0x80000000u) ? ~bits : (bits | 0x80000000u);
        unsigned pos = rb[rr[k]] + lp[k];
        unsigned slot = (rloc[rr[k]] + lp[k]) & 0x7FFu;
        keys1[pos] = ((u64)mk << 32) | ((u64)(ids[k] << 11)) | (u64)slot;
        pay1[pos] = make_float2(yv[k], ev[k] * ev[k]);
    }
}

__device__ __forceinline__ float decode_key(unsigned h) {
    unsigned b = (h & 0x80000000u) ? (h ^ 0x80000000u) : ~h;
    return __uint_as_float(b);
}

// ------- fused region sort + interleaved (t,y,d) emit: 16 buckets/block ------
__global__ __launch_bounds__(256) void sort_k(const u64* __restrict__ keys1,
                                              const float2* __restrict__ pay1,
                                              const unsigned* __restrict__ roff,
                                              float4* __restrict__ tyd,
                                              float scale) {
    __shared__ u64 sk[16 * BCAP];
    __shared__ float2 sp[RCAP];
    __shared__ unsigned lh[16], pre[16];
    const int r = blockIdx.x;
    const int tid = threadIdx.x;
    for (int v = tid; v < 16 * BCAP; v += 256) sk[v] = ~0ull;
    if (tid < 16) lh[tid] = 0u;
    __syncthreads();
    const unsigned s = roff[r], e = roff[r + 1];
    for (unsigned u = s + tid; u < e; u += 256) {
        if (u - s < (unsigned)RCAP) sp[u - s] = pay1[u];
        u64 kk = keys1[u];
        int b16 = bucket_of(decode_key((unsigned)(kk >> 32)), scale) & 15;
        unsigned lp = atomicAdd(&lh[b16], 1u);
        if (lp < (unsigned)BCAP) sk[b16 * BCAP + lp] = kk;
    }
    __syncthreads();
    if (tid == 0) {                       // local bucket prefix (16 values)
        unsigned acc = 0;
#pragma unroll
        for (int c = 0; c < 16; ++c) {
            pre[c] = acc;
            unsigned cc = lh[c];
            acc += (cc > (unsigned)BCAP) ? (unsigned)BCAP : cc;
        }
    }
    // 16 independent 128-key bitonic sorts (1024 pairs/phase, 4 iters/thread)
    for (int k = 2; k <= BCAP; k <<= 1) {
        for (int j = k >> 1; j >= 1; j >>= 1) {
#pragma unroll
            for (int it = 0; it < 4; ++it) {
                int w = it * 256 + tid;
                int q = w >> 6, p = w & 63;
                int i = ((p & ~(j - 1)) << 1) | (p & (j - 1));
                int si = q * BCAP + i, sp_ = si + j;
                bool up = ((i & k) == 0);
                u64 a = sk[si], bb = sk[sp_];
                if ((a > bb) == up) { sk[si] = bb; sk[sp_] = a; }
            }
            __syncthreads();
        }
    }
#pragma unroll
    for (int cp = 0; cp < 8; ++cp) {      // two buckets per pass (256 threads)
        int c = cp * 2 + (tid >> 7);
        int el = tid & 127;
        unsigned cc = lh[c]; cc = (cc > (unsigned)BCAP) ? (unsigned)BCAP : cc;
        if (el < (int)cc) {
            u64 kk = sk[c * BCAP + el];
            unsigned pos = s + pre[c] + el;
            float2 yd = sp[(unsigned)(kk & 0x7FFull)];
            tyd[pos] = make_float4(decode_key((unsigned)(kk >> 32)), yd.x, yd.y, 0.0f);
        }
    }
}

// ---------------- DPP helpers (all perms confined to 8-lane groups) ----------
#define DPPMOV(x, ctrl) __int_as_float(__builtin_amdgcn_update_dpp( \
        0, __float_as_int(x), (ctrl), 0xF, 0xF, true))
#define GSUM8(s, x) { s = (x) + DPPMOV((x), 0xB1); s += DPPMOV(s, 0x4E); s += DPPMOV(s, 0x141); }
#define GATHER8(v, x) { \
    v[0] = (x); v[1] = DPPMOV((x), 0xB1); v[2] = DPPMOV((x), 0x4E); \
    v[3] = DPPMOV(v[1], 0x4E); v[7] = DPPMOV((x), 0x141); \
    v[6] = DPPMOV(v[1], 0x141); v[5] = DPPMOV(v[2], 0x141); v[4] = DPPMOV(v[3], 0x141); }

// ---------------- Kalman: 8 chunks/wave, 8 lanes/chunk, row-per-lane ---------
// CHUNK=32 -> 4096 waves = 4 waves/SIMD (latency hiding). Single float4
// (t,y,d) stream; one ds_read_b128 per step, conflict-free interleave.
// Fake prefix entries (chunk 0 warm): dt=0, d=+inf -> K=0, exact no-op.
__global__ __launch_bounds__(64) void kalman8(
    const float4* __restrict__ tyd, const float* __restrict__ lkp,
    float* __restrict__ llp) {
    __shared__ float4 sty[SLEN * 8];
    const int lane = threadIdx.x & 63;
    const int g = lane >> 3, l = lane & 7;
    const int bi = blockIdx.x;
    const long base = (long)bi * (CPW * CHUNK) - WARM;

    const float INF = __builtin_huge_valf();
    const float4 e0 = tyd[0];
    for (int p = lane; p < CPW * SLEN; p += 64) {
        int gg = p / SLEN, v = p - gg * SLEN;
        long gi = base + gg * CHUNK + v;
        float4 f = (gi >= 0) ? tyd[gi] : make_float4(e0.x, 0.0f, INF, 0.0f);
        sty[v * 8 + ((gg + v) & 7)] = f;
    }
    long gp = base + g * CHUNK - 1;
    float stp = (gp >= 0) ? tyd[gp].x : e0.x;
    __syncthreads();

    const float L2E = 1.44269504088896340736f;
    const float LN2 = 0.6931471805599453f;
    const float c_own = -L2E * __expf(-lkp[2 * l]);
    const float Pinf  = __expf(2.0f * lkp[2 * l + 1]);

    float P[8];
    P[0] = Pinf;
#pragma unroll
    for (int k = 1; k < 8; ++k) P[k] = 0.0f;
    float m = 0.0f, llog = 0.0f, lvw = 0.0f;

#define KSTEP(LS, SCORED) { \
    const int slot_ = (LS) * 8 + ((g + (LS)) & 7); \
    float4 q4 = sty[slot_]; \
    float dtc = q4.x - stp; stp = q4.x; float yc = q4.y; float dc = q4.z; \
    float phi = __builtin_amdgcn_exp2f(dtc * c_own); \
    float fv[8]; GATHER8(fv, phi) \
    float q0 = phi * phi; \
    float dadd = fmaf(-q0, Pinf, Pinf); \
    float Pp[8]; \
    Pp[0] = fmaf(q0, P[0], dadd); \
    _Pragma("unroll") \
    for (int k = 1; k < 8; ++k) Pp[k] = (phi * fv[k]) * P[k]; \
    float Ph = ((Pp[0] + Pp[1]) + (Pp[2] + Pp[3])) + ((Pp[4] + Pp[5]) + (Pp[6] + Pp[7])); \
    float mp = phi * m; \
    float Ss; GSUM8(Ss, Ph) \
    float ms; GSUM8(ms, mp) \
    float S = Ss + dc; \
    float v = yc - ms; \
    float invS = __builtin_amdgcn_rcpf(S); \
    float w = v * invS; \
    float K = Ph * invS; \
    float pv[8]; GATHER8(pv, Ph) \
    _Pragma("unroll") \
    for (int k = 0; k < 8; ++k) P[k] = fmaf(-K, pv[k], Pp[k]); \
    m = fmaf(Ph, w, mp); \
    if (SCORED) { llog += __builtin_amdgcn_logf(S); lvw = fmaf(v, w, lvw); } }

    for (int ls = 0; ls < WARM; ls += PD) {
#pragma unroll
        for (int u = 0; u < PD; ++u) KSTEP(ls + u, false)
    }
    for (int ls = WARM; ls < SLEN; ls += PD) {
#pragma unroll
        for (int u = 0; u < PD; ++u) KSTEP(ls + u, true)
    }
#undef KSTEP

    if (l == 0)
        llp[bi * CPW + g] = -0.5f * (CHUNK * LOG2PI_F + LN2 * llog + lvw);
}

// ---------------- deterministic final reduction ------------------------------
__global__ __launch_bounds__(256) void reduce_ll(const float* __restrict__ llp,
                                                 float* __restrict__ out, int g) {
    __shared__ float sred[4];
    int tid = threadIdx.x;
    float s = 0.0f;
    for (int i = tid; i < g; i += 256) s += llp[i];
    for (int m = 1; m < 64; m <<= 1) s += __shfl_xor(s, m);
    if ((tid & 63) == 0) sred[tid >> 6] = s;
    __syncthreads();
    if (tid == 0) out[0] = sred[0] + sred[1] + sred[2] + sred[3];
}

extern "C" void kernel_launch(void* const* d_in, const int* in_sizes, int n_in,
                              void* d_out, int out_size, void* d_ws, size_t ws_size,
                              hipStream_t stream) {
    const float* t    = (const float*)d_in[0];
    const float* y    = (const float*)d_in[1];
    const float* yerr = (const float*)d_in[2];
    const float* lkp  = (const float*)d_in[3];
    float* out = (float*)d_out;
    const int n = in_sizes[0];  // 1048576 = 2^20

    u64*      keys1 = (u64*)d_ws;                                // [0, 8n)
    float2*   pay1  = (float2*)((char*)d_ws + (size_t)n * 8);    // [8n, 16n)
    float4*   tyd   = (float4*)((char*)d_ws + (size_t)n * 16);   // [16n, 32n)
    float*    llp   = (float*)((char*)d_ws + (size_t)n * 32);    // 32768 floats
    unsigned* hp    = (unsigned*)(llp + 32768);                  // HBLK*NR
    unsigned* roff  = hp + HBLK * NR;     // NR+1
    unsigned* rcnt  = roff + NR + 64;     // NR

    const float scale = (float)NB / ((float)n / 10.0f);
    const int n4 = n / 4;              // 262144

    hist_k<<<HBLK, 256, 0, stream>>>((const float4*)t, hp, scale, n4);
    scan_k<<<1, 1024, 0, stream>>>(hp, roff, rcnt);
    scatter1<<<n4 / 2048, 1024, 0, stream>>>((const float4*)t, (const float4*)y,
                                             (const float4*)yerr, roff, rcnt,
                                             keys1, pay1, scale);
    sort_k<<<NR, 256, 0, stream>>>(keys1, pay1, roff, tyd, scale);

    const int G = n / CHUNK;             // 32768 chunks
    kalman8<<<G / CPW, 64, 0, stream>>>(tyd, lkp, llp);
    reduce_ll<<<1, 256, 0, stream>>>(llp, out, G);
}

// Round 20
// 105.865 us; speedup vs baseline: 1.1426x; 1.1426x over previous
//
#include <hip/hip_runtime.h>
#include <stdint.h>

typedef unsigned long long u64;

#define CHUNK 64
#define WARM  8
#define SLEN  (WARM + CHUNK)        // 72 steps per chunk window
#define CPW   8                     // chunks per wave (8 lanes each)
#define PD    8
#define NB    16384
#define NR    1024                  // regions of 16 buckets
#define BCAP  128                   // max keys per bucket (Poisson mean 64)
#define RCAP  2048                  // max elems per region (mean 1024)
#define HBLK  64                    // hist partial blocks
#define LOG2PI_F 1.8378770664093453f

// ---------------- region histogram: per-block partials, no atomics -----------
__device__ __forceinline__ int bucket_of(float tv, float scale) {
    int b = (int)(tv * scale);
    return b > (NB - 1) ? (NB - 1) : (b < 0 ? 0 : b);
}

__global__ __launch_bounds__(256) void hist_k(const float4* __restrict__ t4,
                                              unsigned* __restrict__ hp,
                                              float scale, int n4) {
    __shared__ unsigned lh[NR];
    for (int v = threadIdx.x; v < NR; v += 256) lh[v] = 0u;
    __syncthreads();
    for (int i = blockIdx.x * 256 + threadIdx.x; i < n4; i += gridDim.x * 256) {
        float4 tv = t4[i];
        atomicAdd(&lh[bucket_of(tv.x, scale) >> 4], 1u);
        atomicAdd(&lh[bucket_of(tv.y, scale) >> 4], 1u);
        atomicAdd(&lh[bucket_of(tv.z, scale) >> 4], 1u);
        atomicAdd(&lh[bucket_of(tv.w, scale) >> 4], 1u);
    }
    __syncthreads();
    for (int v = threadIdx.x; v < NR; v += 256)
        hp[blockIdx.x * NR + v] = lh[v];
}

// ---- region scan: sum 64 partials per region, scan 1024 (1 block) -----------
__global__ __launch_bounds__(1024) void scan_k(const unsigned* __restrict__ hp,
                                               unsigned* __restrict__ roff,
                                               unsigned* __restrict__ rcnt) {
    __shared__ unsigned ws[16];
    const int r = threadIdx.x;           // 0..1023 = region
    unsigned tot = 0;
#pragma unroll 8
    for (int b = 0; b < HBLK; ++b) tot += hp[b * NR + r];
    unsigned s = tot;                    // inclusive scan within wave
#pragma unroll
    for (int d = 1; d < 64; d <<= 1) {
        unsigned v = __shfl_up(s, d);
        if ((r & 63) >= d) s += v;
    }
    if ((r & 63) == 63) ws[r >> 6] = s;
    __syncthreads();
    if (r < 16) {
        unsigned v = ws[r];
#pragma unroll
        for (int d = 1; d < 16; d <<= 1) {
            unsigned x = __shfl_up(v, d);
            if (r >= d) v += x;
        }
        ws[r] = v;
    }
    __syncthreads();
    unsigned wbase = (r >= 64) ? ws[(r >> 6) - 1] : 0u;
    unsigned excl = wbase + s - tot;
    roff[r] = excl; rcnt[r] = excl;
    if (r == NR - 1) roff[NR] = excl + tot;
}

// ------- scatter: block-aggregated keys + (y,d) payload into 1024 regions ----
// key = tbits<<32 | idx<<11 | slot (slot = pos within region, 11 bits).
// Order is (tbits, idx); idx unique -> slot never affects order (determinism).
__global__ __launch_bounds__(1024) void scatter1(const float4* __restrict__ t4,
                                                 const float4* __restrict__ y4,
                                                 const float4* __restrict__ e4,
                                                 const unsigned* __restrict__ roff,
                                                 unsigned* __restrict__ rcnt,
                                                 u64* __restrict__ keys1,
                                                 float2* __restrict__ pay1,
                                                 float scale) {
    __shared__ unsigned lh[NR], rb[NR], rloc[NR];
    const int tid = threadIdx.x;
    lh[tid] = 0u;
    __syncthreads();
    const int i0 = blockIdx.x * 2048 + tid;     // 2048 float4 per block
    float4 a = t4[i0], b = t4[i0 + 1024];
    float4 ya = y4[i0], yb = y4[i0 + 1024];
    float4 ea = e4[i0], eb = e4[i0 + 1024];
    float tv[8] = {a.x, a.y, a.z, a.w, b.x, b.y, b.z, b.w};
    float yv[8] = {ya.x, ya.y, ya.z, ya.w, yb.x, yb.y, yb.z, yb.w};
    float ev[8] = {ea.x, ea.y, ea.z, ea.w, eb.x, eb.y, eb.z, eb.w};
    unsigned id0 = 4u * (unsigned)i0, id1 = 4u * (unsigned)(i0 + 1024);
    unsigned ids[8] = {id0, id0 + 1, id0 + 2, id0 + 3,
                       id1, id1 + 1, id1 + 2, id1 + 3};
    int rr[8]; unsigned lp[8];
#pragma unroll
    for (int k = 0; k < 8; ++k) {
        rr[k] = bucket_of(tv[k], scale) >> 4;
        lp[k] = atomicAdd(&lh[rr[k]], 1u);
    }
    __syncthreads();
    {
        unsigned c = lh[tid];
        unsigned base = c ? atomicAdd(&rcnt[tid], c) : 0u;
        rb[tid] = base;
        rloc[tid] = base - roff[tid];
    }
    __syncthreads();
#pragma unroll
    for (int k = 0; k < 8; ++k) {
        unsigned bits = __float_as_uint(tv[k]);
        unsigned mk = (bits & 0x80000000u) ? ~bits : (bits | 0x80000000u);
        unsigned pos = rb[rr[k]] + lp[k];
        unsigned slot = (rloc[rr[k]] + lp[k]) & 0x7FFu;
        keys1[pos] = ((u64)mk << 32) | ((u64)(ids[k] << 11)) | (u64)slot;
        pay1[pos] = make_float2(yv[k], ev[k] * ev[k]);
    }
}

__device__ __forceinline__ float decode_key(unsigned h) {
    unsigned b = (h & 0x80000000u) ? (h ^ 0x80000000u) : ~h;
    return __uint_as_float(b);
}

// ------- fused region sort + payload emit: 16 buckets/block ------------------
__global__ __launch_bounds__(256) void sort_k(const u64* __restrict__ keys1,
                                              const float2* __restrict__ pay1,
                                              const unsigned* __restrict__ roff,
                                              float* __restrict__ tS,
                                              float* __restrict__ ysA,
                                              float* __restrict__ dgA,
                                              float scale) {
    __shared__ u64 sk[16 * BCAP];
    __shared__ float2 sp[RCAP];
    __shared__ unsigned lh[16], pre[16];
    const int r = blockIdx.x;
    const int tid = threadIdx.x;
    for (int v = tid; v < 16 * BCAP; v += 256) sk[v] = ~0ull;
    if (tid < 16) lh[tid] = 0u;
    __syncthreads();
    const unsigned s = roff[r], e = roff[r + 1];
    for (unsigned u = s + tid; u < e; u += 256) {
        if (u - s < (unsigned)RCAP) sp[u - s] = pay1[u];
        u64 kk = keys1[u];
        int b16 = bucket_of(decode_key((unsigned)(kk >> 32)), scale) & 15;
        unsigned lp = atomicAdd(&lh[b16], 1u);
        if (lp < (unsigned)BCAP) sk[b16 * BCAP + lp] = kk;
    }
    __syncthreads();
    if (tid == 0) {                       // local bucket prefix (16 values)
        unsigned acc = 0;
#pragma unroll
        for (int c = 0; c < 16; ++c) {
            pre[c] = acc;
            unsigned cc = lh[c];
            acc += (cc > (unsigned)BCAP) ? (unsigned)BCAP : cc;
        }
    }
    // 16 independent 128-key bitonic sorts (1024 pairs/phase, 4 iters/thread)
    for (int k = 2; k <= BCAP; k <<= 1) {
        for (int j = k >> 1; j >= 1; j >>= 1) {
#pragma unroll
            for (int it = 0; it < 4; ++it) {
                int w = it * 256 + tid;
                int q = w >> 6, p = w & 63;
                int i = ((p & ~(j - 1)) << 1) | (p & (j - 1));
                int si = q * BCAP + i, sp_ = si + j;
                bool up = ((i & k) == 0);
                u64 a = sk[si], bb = sk[sp_];
                if ((a > bb) == up) { sk[si] = bb; sk[sp_] = a; }
            }
            __syncthreads();
        }
    }
#pragma unroll
    for (int cp = 0; cp < 8; ++cp) {      // two buckets per pass (256 threads)
        int c = cp * 2 + (tid >> 7);
        int el = tid & 127;
        unsigned cc = lh[c]; cc = (cc > (unsigned)BCAP) ? (unsigned)BCAP : cc;
        if (el < (int)cc) {
            u64 kk = sk[c * BCAP + el];
            unsigned pos = s + pre[c] + el;
            float2 yd = sp[(unsigned)(kk & 0x7FFull)];
            tS[pos] = decode_key((unsigned)(kk >> 32));
            ysA[pos] = yd.x;
            dgA[pos] = yd.y;
        }
    }
}

// ---------------- DPP helpers (all perms confined to 8-lane groups) ----------
#define DPPMOV(x, ctrl) __int_as_float(__builtin_amdgcn_update_dpp( \
        0, __float_as_int(x), (ctrl), 0xF, 0xF, true))
#define GSUM8(s, x) { s = (x) + DPPMOV((x), 0xB1); s += DPPMOV(s, 0x4E); s += DPPMOV(s, 0x141); }
#define GATHER8(v, x) { \
    v[0] = (x); v[1] = DPPMOV((x), 0xB1); v[2] = DPPMOV((x), 0x4E); \
    v[3] = DPPMOV(v[1], 0x4E); v[7] = DPPMOV((x), 0x141); \
    v[6] = DPPMOV(v[1], 0x141); v[5] = DPPMOV(v[2], 0x141); v[4] = DPPMOV(v[3], 0x141); }

// ---------------- Kalman: 8 chunks/wave, 8 lanes/chunk, row-per-lane ---------
// (t,y,d) packed per slot -> single ds_read_b128 per step, conflict-free.
// Fake prefix entries (chunk 0 warm): dt=0, d=+inf -> K=0, exact no-op.
__global__ __launch_bounds__(64) void kalman8(
    const float* __restrict__ tS, const float* __restrict__ ysA,
    const float* __restrict__ dgA, const float* __restrict__ lkp,
    float* __restrict__ llp) {
    __shared__ float4 sty[SLEN * 8];
    const int lane = threadIdx.x & 63;
    const int g = lane >> 3, l = lane & 7;
    const int bi = blockIdx.x;
    const long base = (long)bi * (CPW * CHUNK) - WARM;

    const float INF = __builtin_huge_valf();
    const float t0 = tS[0];
#pragma unroll
    for (int gg = 0; gg < CPW; ++gg) {
        for (int v = lane; v < SLEN; v += 64) {
            long gi = base + gg * CHUNK + v;
            float tv, yv, dv;
            if (gi >= 0) { tv = tS[gi]; yv = ysA[gi]; dv = dgA[gi]; }
            else { tv = t0; yv = 0.0f; dv = INF; }
            sty[v * 8 + ((gg + v) & 7)] = make_float4(tv, yv, dv, 0.0f);
        }
    }
    long gp = base + g * CHUNK - 1;
    float stp = (gp >= 0) ? tS[gp] : t0;
    __syncthreads();

    const float L2E = 1.44269504088896340736f;
    const float LN2 = 0.6931471805599453f;
    const float c_own = -L2E * __expf(-lkp[2 * l]);
    const float Pinf  = __expf(2.0f * lkp[2 * l + 1]);

    float P[8];
    P[0] = Pinf;
#pragma unroll
    for (int k = 1; k < 8; ++k) P[k] = 0.0f;
    float m = 0.0f, llog = 0.0f, lvw = 0.0f;

#define KSTEP(LS, SCORED) { \
    const int slot_ = (LS) * 8 + ((g + (LS)) & 7); \
    float4 q4 = sty[slot_]; \
    float dtc = q4.x - stp; stp = q4.x; float yc = q4.y; float dc = q4.z; \
    float phi = __builtin_amdgcn_exp2f(dtc * c_own); \
    float fv[8]; GATHER8(fv, phi) \
    float q0 = phi * phi; \
    float dadd = fmaf(-q0, Pinf, Pinf); \
    float Pp[8]; \
    Pp[0] = fmaf(q0, P[0], dadd); \
    _Pragma("unroll") \
    for (int k = 1; k < 8; ++k) Pp[k] = (phi * fv[k]) * P[k]; \
    float Ph = ((Pp[0] + Pp[1]) + (Pp[2] + Pp[3])) + ((Pp[4] + Pp[5]) + (Pp[6] + Pp[7])); \
    float mp = phi * m; \
    float Ss; GSUM8(Ss, Ph) \
    float ms; GSUM8(ms, mp) \
    float S = Ss + dc; \
    float v = yc - ms; \
    float invS = __builtin_amdgcn_rcpf(S); \
    float w = v * invS; \
    float K = Ph * invS; \
    float pv[8]; GATHER8(pv, Ph) \
    _Pragma("unroll") \
    for (int k = 0; k < 8; ++k) P[k] = fmaf(-K, pv[k], Pp[k]); \
    m = fmaf(Ph, w, mp); \
    if (SCORED) { llog += __builtin_amdgcn_logf(S); lvw = fmaf(v, w, lvw); } }

    for (int ls = 0; ls < WARM; ls += PD) {
#pragma unroll
        for (int u = 0; u < PD; ++u) KSTEP(ls + u, false)
    }
    for (int ls = WARM; ls < SLEN; ls += PD) {
#pragma unroll
        for (int u = 0; u < PD; ++u) KSTEP(ls + u, true)
    }
#undef KSTEP

    if (l == 0)
        llp[bi * CPW + g] = -0.5f * (CHUNK * LOG2PI_F + LN2 * llog + lvw);
}

// ---------------- deterministic final reduction ------------------------------
__global__ __launch_bounds__(256) void reduce_ll(const float* __restrict__ llp,
                                                 float* __restrict__ out, int g) {
    __shared__ float sred[4];
    int tid = threadIdx.x;
    float s = 0.0f;
    for (int i = tid; i < g; i += 256) s += llp[i];
    for (int m = 1; m < 64; m <<= 1) s += __shfl_xor(s, m);
    if ((tid & 63) == 0) sred[tid >> 6] = s;
    __syncthreads();
    if (tid == 0) out[0] = sred[0] + sred[1] + sred[2] + sred[3];
}

extern "C" void kernel_launch(void* const* d_in, const int* in_sizes, int n_in,
                              void* d_out, int out_size, void* d_ws, size_t ws_size,
                              hipStream_t stream) {
    const float* t    = (const float*)d_in[0];
    const float* y    = (const float*)d_in[1];
    const float* yerr = (const float*)d_in[2];
    const float* lkp  = (const float*)d_in[3];
    float* out = (float*)d_out;
    const int n = in_sizes[0];  // 1048576 = 2^20

    u64*      keys1 = (u64*)d_ws;                                // [0, 8n)
    float2*   pay1  = (float2*)((char*)d_ws + (size_t)n * 8);    // [8n, 16n)
    float*    tS    = (float*)((char*)d_ws + (size_t)n * 16);    // [16n, 20n)
    float*    ysA   = (float*)((char*)d_ws + (size_t)n * 20);    // [20n, 24n)
    float*    dgA   = (float*)((char*)d_ws + (size_t)n * 24);    // [24n, 28n)
    float*    llp   = (float*)((char*)d_ws + (size_t)n * 28);    // 16384 floats
    unsigned* hp    = (unsigned*)(llp + 16384);                  // HBLK*NR
    unsigned* roff  = hp + HBLK * NR;     // NR+1
    unsigned* rcnt  = roff + NR + 64;     // NR

    const float scale = (float)NB / ((float)n / 10.0f);
    const int n4 = n / 4;              // 262144

    hist_k<<<HBLK, 256, 0, stream>>>((const float4*)t, hp, scale, n4);
    scan_k<<<1, 1024, 0, stream>>>(hp, roff, rcnt);
    scatter1<<<n4 / 2048, 1024, 0, stream>>>((const float4*)t, (const float4*)y,
                                             (const float4*)yerr, roff, rcnt,
                                             keys1, pay1, scale);
    sort_k<<<NR, 256, 0, stream>>>(keys1, pay1, roff, tS, ysA, dgA, scale);

    const int G = n / CHUNK;             // 16384 chunks
    kalman8<<<G / CPW, 64, 0, stream>>>(tS, ysA, dgA, lkp, llp);
    reduce_ll<<<1, 256, 0, stream>>>(llp, out, G);
}